// Round 1
// baseline (20369.145 us; speedup 1.0000x reference)
//
#include <hip/hip_runtime.h>
#include <hip/hip_bf16.h>
#include <math.h>

#define NMAX 200
#define BATCH 512
#define LAT 128
#define EH 256
#define DH 512
#define NMIX 20

__device__ __forceinline__ float sigm(float x) { return 1.0f / (1.0f + __expf(-x)); }

// ---------------- encoder step: both directions, fused x@Wih + h@Whh + LSTM pointwise ----------------
__global__ __launch_bounds__(256) void enc_step(
    const float* __restrict__ x,
    const float* __restrict__ Wih_f, const float* __restrict__ Whh_f, const float* __restrict__ b_f,
    const float* __restrict__ Wih_b, const float* __restrict__ Whh_b, const float* __restrict__ b_b,
    const float* __restrict__ hfp, float* __restrict__ hfn, float* __restrict__ cf,
    const float* __restrict__ hbp, float* __restrict__ hbn, float* __restrict__ cb,
    int t)
{
    const int dir = blockIdx.z;
    const float* Wih  = dir ? Wih_b : Wih_f;
    const float* Whh  = dir ? Whh_b : Whh_f;
    const float* bias = dir ? b_b   : b_f;
    const float* hp   = dir ? hbp   : hfp;
    float* hn         = dir ? hbn   : hfn;
    float* c          = dir ? cb    : cf;
    const int ts = dir ? (NMAX - t) : t;          // bwd scans x reversed
    const float* xt = x + ts * (BATCH * 5);

    __shared__ float hs[16 * EH];
    __shared__ float xs[16][5];
    const int row0 = blockIdx.y * 16;
    const int tid = threadIdx.x;
    {
        const float4* src = (const float4*)(hp + row0 * EH);
        float4* dst = (float4*)hs;
        for (int i = tid; i < 16 * EH / 4; i += 256) dst[i] = src[i];
    }
    if (tid < 80) xs[tid / 5][tid % 5] = xt[(row0 + tid / 5) * 5 + tid % 5];
    __syncthreads();

    const int jl = tid & 31, rp = tid >> 5;
    const int j = blockIdx.x * 32 + jl;
    const float* w = Whh + j;
    const float* h0p = hs + (rp * 2) * EH;
    const float* h1p = hs + (rp * 2 + 1) * EH;
    float a00 = 0, a01 = 0, a02 = 0, a03 = 0, a10 = 0, a11 = 0, a12 = 0, a13 = 0;
#pragma unroll 8
    for (int k = 0; k < EH; ++k) {
        float w0 = w[k * 1024], w1 = w[k * 1024 + 256], w2 = w[k * 1024 + 512], w3 = w[k * 1024 + 768];
        float h0 = h0p[k], h1 = h1p[k];
        a00 += h0 * w0; a01 += h0 * w1; a02 += h0 * w2; a03 += h0 * w3;
        a10 += h1 * w0; a11 += h1 * w1; a12 += h1 * w2; a13 += h1 * w3;
    }
    const float* wi = Wih + j;
#pragma unroll
    for (int i = 0; i < 5; ++i) {
        float w0 = wi[i * 1024], w1 = wi[i * 1024 + 256], w2 = wi[i * 1024 + 512], w3 = wi[i * 1024 + 768];
        float x0 = xs[rp * 2][i], x1 = xs[rp * 2 + 1][i];
        a00 += x0 * w0; a01 += x0 * w1; a02 += x0 * w2; a03 += x0 * w3;
        a10 += x1 * w0; a11 += x1 * w1; a12 += x1 * w2; a13 += x1 * w3;
    }
    const float bi = bias[j], bf2 = bias[256 + j], bg = bias[512 + j], bo = bias[768 + j];
    {
        int b = row0 + rp * 2;
        float gi = a00 + bi, gf = a01 + bf2, gg = a02 + bg, go = a03 + bo;
        float cv = c[b * EH + j];
        cv = sigm(gf) * cv + sigm(gi) * tanhf(gg);
        c[b * EH + j] = cv;
        hn[b * EH + j] = sigm(go) * tanhf(cv);
    }
    {
        int b = row0 + rp * 2 + 1;
        float gi = a10 + bi, gf = a11 + bf2, gg = a12 + bg, go = a13 + bo;
        float cv = c[b * EH + j];
        cv = sigm(gf) * cv + sigm(gi) * tanhf(gg);
        c[b * EH + j] = cv;
        hn[b * EH + j] = sigm(go) * tanhf(cv);
    }
}

// ---------------- latent 1: mean/logvar/z ----------------
__global__ __launch_bounds__(256) void latent1(
    const float* __restrict__ hf, const float* __restrict__ hb,
    const float* __restrict__ W_mu, const float* __restrict__ b_mu,
    const float* __restrict__ W_lv, const float* __restrict__ b_lv,
    const float* __restrict__ eps, float* __restrict__ z, float* __restrict__ out)
{
    __shared__ float hs[16 * 512];
    const int row0 = blockIdx.x * 16;
    const int tid = threadIdx.x;
    {
        float4* dst = (float4*)hs;
        const float4* f4 = (const float4*)(hf + row0 * EH);
        const float4* b4 = (const float4*)(hb + row0 * EH);
        for (int i = tid; i < 2048; i += 256) {
            int r = i >> 7, rem = i & 127;
            dst[i] = (rem < 64) ? f4[r * 64 + rem] : b4[r * 64 + (rem - 64)];
        }
    }
    __syncthreads();
    for (int p = tid; p < 2048; p += 256) {
        int r = p >> 7, cc = p & 127;
        const float* hr = hs + r * 512;
        float m = 0, lv = 0;
#pragma unroll 8
        for (int k = 0; k < 512; ++k) {
            float hv = hr[k];
            m  += hv * W_mu[k * 128 + cc];
            lv += hv * W_lv[k * 128 + cc];
        }
        m += b_mu[cc]; lv += b_lv[cc];
        int b = row0 + r;
        out[512002 + b * 128 + cc] = m;
        out[577538 + b * 128 + cc] = lv;
        z[b * 128 + cc] = m + __expf(0.5f * lv) * eps[b * 128 + cc];
    }
}

// ---------------- latent 2: hc0 = tanh(z@W_fc_in+b), and zpre = z@dec_Wih[5:] + dec_b ----------------
__global__ __launch_bounds__(256) void latent2(
    const float* __restrict__ z, const float* __restrict__ W_fc, const float* __restrict__ b_fc,
    const float* __restrict__ dWih, const float* __restrict__ dec_b,
    float* __restrict__ h0, float* __restrict__ c0, float* __restrict__ zpre)
{
    __shared__ float zs[16 * 128];
    const int row0 = blockIdx.y * 16;
    const int tid = threadIdx.x;
    {
        float4* dst = (float4*)zs;
        const float4* src = (const float4*)(z + row0 * 128);
        for (int i = tid; i < 512; i += 256) dst[i] = src[i];
    }
    __syncthreads();
    const int colbase = blockIdx.x * 128;
    for (int p = tid; p < 16 * 128; p += 256) {
        int r = p >> 7, cl = p & 127;
        int col = colbase + cl;
        const float* zr = zs + r * 128;
        int b = row0 + r;
        if (col < 1024) {
            float acc = 0;
#pragma unroll 8
            for (int k = 0; k < 128; ++k) acc += zr[k] * W_fc[k * 1024 + col];
            float v = tanhf(acc + b_fc[col]);
            if (col < 512) h0[b * 512 + col] = v;
            else           c0[b * 512 + (col - 512)] = v;
        } else {
            int n = col - 1024;
            float acc = 0;
#pragma unroll 8
            for (int k = 0; k < 128; ++k) acc += zr[k] * dWih[(5 + k) * 2048 + n];
            zpre[b * 2048 + n] = acc + dec_b[n];
        }
    }
}

// ---------------- decoder LSTM cell ----------------
__global__ __launch_bounds__(256) void dec_cell(
    const float* __restrict__ dWih, const float* __restrict__ dWhh,
    const float* __restrict__ zpre, const float* __restrict__ strokes,
    const float* __restrict__ hp, float* __restrict__ hn, float* __restrict__ c,
    int s)
{
    __shared__ float hs[16 * DH];
    __shared__ float xs[16][5];
    const int row0 = blockIdx.y * 16;
    const int tid = threadIdx.x;
    {
        const float4* src = (const float4*)(hp + row0 * DH);
        float4* dst = (float4*)hs;
        for (int i = tid; i < 16 * DH / 4; i += 256) dst[i] = src[i];
    }
    if (tid < 80) {
        int r = tid / 5, i = tid % 5;
        float v = (s == 0) ? ((i == 2) ? 1.0f : 0.0f)
                           : strokes[(s - 1) * (BATCH * 5) + (row0 + r) * 5 + i];
        xs[r][i] = v;
    }
    __syncthreads();

    const int jl = tid & 31, rp = tid >> 5;
    const int j = blockIdx.x * 32 + jl;
    const float* w = dWhh + j;
    const float* h0p = hs + (rp * 2) * DH;
    const float* h1p = hs + (rp * 2 + 1) * DH;
    float a00 = 0, a01 = 0, a02 = 0, a03 = 0, a10 = 0, a11 = 0, a12 = 0, a13 = 0;
#pragma unroll 8
    for (int k = 0; k < DH; ++k) {
        float w0 = w[k * 2048], w1 = w[k * 2048 + 512], w2 = w[k * 2048 + 1024], w3 = w[k * 2048 + 1536];
        float h0 = h0p[k], h1 = h1p[k];
        a00 += h0 * w0; a01 += h0 * w1; a02 += h0 * w2; a03 += h0 * w3;
        a10 += h1 * w0; a11 += h1 * w1; a12 += h1 * w2; a13 += h1 * w3;
    }
    const float* wi = dWih + j;
#pragma unroll
    for (int i = 0; i < 5; ++i) {
        float w0 = wi[i * 2048], w1 = wi[i * 2048 + 512], w2 = wi[i * 2048 + 1024], w3 = wi[i * 2048 + 1536];
        float x0 = xs[rp * 2][i], x1 = xs[rp * 2 + 1][i];
        a00 += x0 * w0; a01 += x0 * w1; a02 += x0 * w2; a03 += x0 * w3;
        a10 += x1 * w0; a11 += x1 * w1; a12 += x1 * w2; a13 += x1 * w3;
    }
    {
        int b = row0 + rp * 2;
        const float* zp = zpre + b * 2048;
        float gi = a00 + zp[j], gf = a01 + zp[512 + j], gg = a02 + zp[1024 + j], go = a03 + zp[1536 + j];
        float cv = c[b * DH + j];
        cv = sigm(gf) * cv + sigm(gi) * tanhf(gg);
        c[b * DH + j] = cv;
        hn[b * DH + j] = sigm(go) * tanhf(cv);
    }
    {
        int b = row0 + rp * 2 + 1;
        const float* zp = zpre + b * 2048;
        float gi = a10 + zp[j], gf = a11 + zp[512 + j], gg = a12 + zp[1024 + j], go = a13 + zp[1536 + j];
        float cv = c[b * DH + j];
        cv = sigm(gf) * cv + sigm(gi) * tanhf(gg);
        c[b * DH + j] = cv;
        hn[b * DH + j] = sigm(go) * tanhf(cv);
    }
}

// ---------------- decoder output head: y = h@W_out + b_out, GMM mixture, losses, stroke ----------------
__global__ __launch_bounds__(256) void dec_out(
    const float* __restrict__ h, const float* __restrict__ W_out, const float* __restrict__ b_out,
    const float* __restrict__ x, const int* __restrict__ N_s, float* __restrict__ out, int s)
{
    __shared__ float hs[8 * DH];
    __shared__ float ys[8][124];
    __shared__ float red_pl[8], red_ol[8];
    const int row0 = blockIdx.x * 8;
    const int tid = threadIdx.x;
    {
        const float4* src = (const float4*)(h + row0 * DH);
        float4* dst = (float4*)hs;
        for (int i = tid; i < 8 * DH / 4; i += 256) dst[i] = src[i];
    }
    __syncthreads();
    for (int p = tid; p < 8 * 123; p += 256) {
        int r = p / 123, cc = p % 123;
        const float* hr = hs + r * DH;
        const float* wc = W_out + cc;
        float acc = 0;
#pragma unroll 8
        for (int k = 0; k < DH; ++k) acc += hr[k] * wc[k * 123];
        ys[r][cc] = acc + b_out[cc];
    }
    __syncthreads();
    if (tid < 8) {
        const int r = tid, b = row0 + r;
        const float* y = ys[r];
        const float* xt = x + (s + 1) * (BATCH * 5) + b * 5;
        const float dx = xt[0], dy = xt[1];
        // pen loss (unmasked)
        float q0 = y[120], q1 = y[121], q2 = y[122];
        float qm = fmaxf(q0, fmaxf(q1, q2));
        float lse = qm + logf(__expf(q0 - qm) + __expf(q1 - qm) + __expf(q2 - qm));
        float pl = -(xt[2] * (q0 - lse) + xt[3] * (q1 - lse) + xt[4] * (q2 - lse));
        // mixture
        float pm = -1e30f;
#pragma unroll
        for (int jj = 0; jj < NMIX; ++jj) pm = fmaxf(pm, y[jj * 6]);
        float S = 0, gp = 0, gx = 0, gy = 0;
#pragma unroll
        for (int jj = 0; jj < NMIX; ++jj) {
            float ph = y[jj * 6], mux = y[jj * 6 + 1], muy = y[jj * 6 + 2];
            float sx = __expf(y[jj * 6 + 3]), sy = __expf(y[jj * 6 + 4]);
            float rho = tanhf(y[jj * 6 + 5]);
            float e = __expf(ph - pm);
            float zx = (dx - mux) / sx, zy = (dy - muy) / sy;
            float om = 1.0f - rho * rho;
            float pdf = __expf(-(zx * zx + zy * zy - 2.0f * rho * zx * zy) / (2.0f * om))
                        * (0.15915494309189535f / (sx * sy * sqrtf(om)));
            S += e; gp += e * pdf; gx += e * mux; gy += e * muy;
        }
        float gmm = gp / S;
        int len = N_s[b];
        float ol = ((s + 1) < len) ? -logf(gmm + 1e-6f) : 0.0f;
        int am = 0; float bv = q0;
        if (q1 > bv) { bv = q1; am = 1; }
        if (q2 > bv) { bv = q2; am = 2; }
        float* so = out + s * (BATCH * 5) + b * 5;
        if ((s + 1) > len) { so[0] = 0; so[1] = 0; so[2] = 0; so[3] = 0; so[4] = 1.0f; }
        else {
            so[0] = gx / S; so[1] = gy / S;
            so[2] = (am == 0) ? 1.0f : 0.0f;
            so[3] = (am == 1) ? 1.0f : 0.0f;
            so[4] = (am == 2) ? 1.0f : 0.0f;
        }
        red_pl[r] = pl; red_ol[r] = ol;
    }
    __syncthreads();
    if (tid == 0) {
        float spl = 0, sol = 0;
        for (int r = 0; r < 8; ++r) { spl += red_pl[r]; sol += red_ol[r]; }
        const float inv = 1.0f / (512.0f * 200.0f);
        atomicAdd(out + 512001, spl * inv);   // pen_loss
        atomicAdd(out + 512000, sol * inv);   // offset_loss
    }
}

extern "C" void kernel_launch(void* const* d_in, const int* in_sizes, int n_in,
                              void* d_out_, int out_size, void* d_ws, size_t ws_size,
                              hipStream_t stream) {
    const float* x         = (const float*)d_in[0];
    const int*   N_s       = (const int*)  d_in[1];
    const float* eps       = (const float*)d_in[2];
    const float* enc_Wih_f = (const float*)d_in[3];
    const float* enc_Whh_f = (const float*)d_in[4];
    const float* enc_b_f   = (const float*)d_in[5];
    const float* enc_Wih_b = (const float*)d_in[6];
    const float* enc_Whh_b = (const float*)d_in[7];
    const float* enc_b_b   = (const float*)d_in[8];
    const float* W_mu      = (const float*)d_in[9];
    const float* b_mu      = (const float*)d_in[10];
    const float* W_logvar  = (const float*)d_in[11];
    const float* b_logvar  = (const float*)d_in[12];
    const float* W_fc_in   = (const float*)d_in[13];
    const float* b_fc_in   = (const float*)d_in[14];
    const float* dec_Wih   = (const float*)d_in[15];
    const float* dec_Whh   = (const float*)d_in[16];
    const float* dec_b     = (const float*)d_in[17];
    const float* W_out     = (const float*)d_in[18];
    const float* b_out     = (const float*)d_in[19];
    float* out = (float*)d_out_;
    float* ws  = (float*)d_ws;

    float* h_f0 = ws + 0;
    float* c_f  = ws + 131072;
    float* h_b0 = ws + 262144;
    float* c_b  = ws + 393216;
    float* h_f1 = ws + 524288;
    float* h_b1 = ws + 655360;
    float* h_d0 = ws + 786432;
    float* h_d1 = ws + 1048576;
    float* c_d  = ws + 1310720;
    float* z    = ws + 1572864;
    float* zpre = ws + 1638400;

    // zero encoder h0/c0 (contiguous block) and d_out tail slots (stroke row 199 + both losses)
    hipMemsetAsync(ws, 0, 524288 * sizeof(float), stream);
    hipMemsetAsync(out + 509440, 0, 2562 * sizeof(float), stream);

    for (int t = 0; t <= NMAX; ++t) {
        float* hfp = (t & 1) ? h_f1 : h_f0; float* hfn = (t & 1) ? h_f0 : h_f1;
        float* hbp = (t & 1) ? h_b1 : h_b0; float* hbn = (t & 1) ? h_b0 : h_b1;
        enc_step<<<dim3(8, 32, 2), 256, 0, stream>>>(
            x, enc_Wih_f, enc_Whh_f, enc_b_f, enc_Wih_b, enc_Whh_b, enc_b_b,
            hfp, hfn, c_f, hbp, hbn, c_b, t);
    }
    // final h is in buffer written by t=200 (even) -> h_f1 / h_b1
    latent1<<<32, 256, 0, stream>>>(h_f1, h_b1, W_mu, b_mu, W_logvar, b_logvar, eps, z, out);
    latent2<<<dim3(24, 32), 256, 0, stream>>>(z, W_fc_in, b_fc_in, dec_Wih, dec_b, h_d0, c_d, zpre);

    for (int s = 0; s < NMAX - 1; ++s) {
        float* hp = (s & 1) ? h_d1 : h_d0;
        float* hn = (s & 1) ? h_d0 : h_d1;
        dec_cell<<<dim3(16, 32), 256, 0, stream>>>(dec_Wih, dec_Whh, zpre, out, hp, hn, c_d, s);
        dec_out<<<64, 256, 0, stream>>>(hn, W_out, b_out, x, N_s, out, s);
    }
}

// Round 2
// 6356.226 us; speedup vs baseline: 3.2046x; 3.2046x over previous
//
#include <hip/hip_runtime.h>
#include <hip/hip_bf16.h>
#include <math.h>

#define NMAX 200
#define BATCH 512
#define EH 256
#define DH 512
#define NMIX 20
#define HE_BLK 131072   // 512*256
#define HD_BLK 262144   // 512*512

typedef unsigned short u16;
typedef __bf16 bfx8 __attribute__((ext_vector_type(8)));
typedef float  fx4  __attribute__((ext_vector_type(4)));
typedef u16    us8  __attribute__((ext_vector_type(8)));

__device__ __forceinline__ float sigm(float x) { return 1.0f / (1.0f + __expf(-x)); }
__device__ __forceinline__ u16 f2bf(float x) {
    unsigned u = __float_as_uint(x);
    unsigned r = u + 0x7fffu + ((u >> 16) & 1u);
    return (u16)(r >> 16);
}
__device__ __forceinline__ float bf2f(u16 h) { return __uint_as_float(((unsigned)h) << 16); }

// ---- LDS tile index with XOR swizzle: tile rows of 64 u16 (128B), byte ^= ((r&7)<<4) ----
__device__ __forceinline__ int ldsidx(int r, int k) { return r * 64 + (k ^ ((r & 7) << 3)); }

// stage A: 32 rows x 64 k (u16), src row-major with stride `stride`
__device__ __forceinline__ void stageA(u16* As, const u16* src, int stride) {
    int t = threadIdx.x;
    int r = t >> 3, k0 = (t & 7) * 8;
    *(us8*)&As[ldsidx(r, k0)] = *(const us8*)&src[r * stride + k0];
}
// stage B: 128 rows(n) x 64 k from wT[n][K]; global n = (r>>5)*GS + j0 + (r&31)
__device__ __forceinline__ void stageB(u16* Bs, const u16* wT, int K, int GS, int j0, int kbase) {
#pragma unroll
    for (int i = 0; i < 4; ++i) {
        int idx = i * 256 + threadIdx.x;
        int r = idx >> 3, k0 = (idx & 7) * 8;
        int n = (r >> 5) * GS + j0 + (r & 31);
        *(us8*)&Bs[ldsidx(r, k0)] = *(const us8*)&wT[n * K + kbase + k0];
    }
}

// one BK=64 chunk of split-precision MFMA: acc += A*B (3 mfma per tile: hh, hl, lh)
__device__ __forceinline__ void gemm_chunk(const u16* As_hi, const u16* As_lo,
                                           const u16* Bs_hi, const u16* Bs_lo,
                                           int wv, int lane, fx4 acc[2][2]) {
    const int ar = lane & 15, kg = (lane >> 4) * 8;
#pragma unroll
    for (int ks = 0; ks < 2; ++ks) {
        const int kk = ks * 32 + kg;
        bfx8 ah[2], al[2], bh[2], bl[2];
#pragma unroll
        for (int mt = 0; mt < 2; ++mt) {
            int r = mt * 16 + ar;
            int idx = ldsidx(r, kk);
            ah[mt] = *(const bfx8*)&As_hi[idx];
            al[mt] = *(const bfx8*)&As_lo[idx];
        }
#pragma unroll
        for (int nt = 0; nt < 2; ++nt) {
            int r = wv * 32 + nt * 16 + ar;
            int idx = ldsidx(r, kk);
            bh[nt] = *(const bfx8*)&Bs_hi[idx];
            bl[nt] = *(const bfx8*)&Bs_lo[idx];
        }
#pragma unroll
        for (int mt = 0; mt < 2; ++mt)
#pragma unroll
            for (int nt = 0; nt < 2; ++nt) {
                acc[mt][nt] = __builtin_amdgcn_mfma_f32_16x16x32_bf16(ah[mt], bh[nt], acc[mt][nt], 0, 0, 0);
                acc[mt][nt] = __builtin_amdgcn_mfma_f32_16x16x32_bf16(ah[mt], bl[nt], acc[mt][nt], 0, 0, 0);
                acc[mt][nt] = __builtin_amdgcn_mfma_f32_16x16x32_bf16(al[mt], bh[nt], acc[mt][nt], 0, 0, 0);
            }
    }
}

// ---------------- prep: split fp32 weight [K][Nsrc] into transposed bf16 hi/lo [Nout][K] ----------------
__global__ __launch_bounds__(256) void prep_split_T(const float* __restrict__ src,
                                                    u16* dhi, u16* dlo, int K, int Nsrc, int Nout) {
    int idx = blockIdx.x * 256 + threadIdx.x;
    if (idx >= Nout * K) return;
    int n = idx / K, k = idx - n * K;
    float v = (n < Nsrc) ? src[k * Nsrc + n] : 0.0f;
    u16 hh = f2bf(v);
    dhi[idx] = hh;
    dlo[idx] = f2bf(v - bf2f(hh));
}

// ---------------- encoder step (both dirs): gates = h@Whh (MFMA split) + x@Wih + b, LSTM pointwise ----------------
__global__ __launch_bounds__(256) void enc_step_m(
    const float* __restrict__ x,
    const float* __restrict__ Wih_f, const float* __restrict__ b_f,
    const float* __restrict__ Wih_b, const float* __restrict__ b_b,
    const u16* whhT,       // [dir][part][1024*256]
    u16* he,               // [buf][dir][part][512*256]
    float* c_base,         // c_f then c_b
    int t)
{
    const int dir = blockIdx.z;
    const int j0 = blockIdx.x * 32;
    const int row0 = blockIdx.y * 32;
    const int pb = t & 1, nb = pb ^ 1;
    const int ts = dir ? (NMAX - t) : t;
    const float* Wih  = dir ? Wih_b : Wih_f;
    const float* bias = dir ? b_b : b_f;
    const u16* wT_hi = whhT + (dir * 2 + 0) * 262144;
    const u16* wT_lo = whhT + (dir * 2 + 1) * 262144;
    const u16* hp_hi = he + ((pb * 2 + dir) * 2 + 0) * HE_BLK;
    const u16* hp_lo = he + ((pb * 2 + dir) * 2 + 1) * HE_BLK;
    u16* hn_hi = he + ((nb * 2 + dir) * 2 + 0) * HE_BLK;
    u16* hn_lo = he + ((nb * 2 + dir) * 2 + 1) * HE_BLK;
    float* c = c_base + dir * 131072;

    __shared__ __align__(16) char smem[40960];
    u16* As_hi = (u16*)smem;            // 4KB
    u16* As_lo = As_hi + 2048;          // 4KB
    u16* Bs_hi = As_lo + 2048;          // 16KB
    u16* Bs_lo = Bs_hi + 8192;          // 16KB
    float (*gL)[32][32] = (float(*)[32][32])(smem + 8192);  // aliases Bs (16KB), used post-GEMM
    __shared__ float xL[32][5];
    __shared__ float WihL[5][128];
    __shared__ float biasL[128];

    const int tid = threadIdx.x;
    const int wv = tid >> 6, lane = tid & 63;
    if (tid < 160) { int r = tid / 5, i = tid % 5; xL[r][i] = x[ts * 2560 + (row0 + r) * 5 + i]; }
    if (tid < 128) {
        biasL[tid] = bias[(tid >> 5) * 256 + j0 + (tid & 31)];
#pragma unroll
        for (int i = 0; i < 5; ++i) WihL[i][tid] = Wih[i * 1024 + (tid >> 5) * 256 + j0 + (tid & 31)];
    }

    fx4 acc[2][2] = {};
    for (int ch = 0; ch < 4; ++ch) {
        if (ch) __syncthreads();
        const int kb = ch * 64;
        stageA(As_hi, hp_hi + row0 * 256 + kb, 256);
        stageA(As_lo, hp_lo + row0 * 256 + kb, 256);
        stageB(Bs_hi, wT_hi, 256, 256, j0, kb);
        stageB(Bs_lo, wT_lo, 256, 256, j0, kb);
        __syncthreads();
        gemm_chunk(As_hi, As_lo, Bs_hi, Bs_lo, wv, lane, acc);
    }
    __syncthreads();   // all compute done before overwriting Bs alias with gL
#pragma unroll
    for (int mt = 0; mt < 2; ++mt)
#pragma unroll
        for (int nt = 0; nt < 2; ++nt)
#pragma unroll
            for (int r2 = 0; r2 < 4; ++r2)
                gL[wv][mt * 16 + (lane >> 4) * 4 + r2][nt * 16 + (lane & 15)] = acc[mt][nt][r2];
    __syncthreads();

    {
        const int j = tid & 31, rq = tid >> 5;
#pragma unroll
        for (int ii = 0; ii < 4; ++ii) {
            const int b = rq + ii * 8;
            float gv[4];
#pragma unroll
            for (int g = 0; g < 4; ++g) {
                float s = gL[g][b][j] + biasL[g * 32 + j];
#pragma unroll
                for (int i = 0; i < 5; ++i) s += xL[b][i] * WihL[i][g * 32 + j];
                gv[g] = s;
            }
            const int gidx = (row0 + b) * 256 + j0 + j;
            float cv = c[gidx];
            cv = sigm(gv[1]) * cv + sigm(gv[0]) * tanhf(gv[2]);
            c[gidx] = cv;
            float hv = sigm(gv[3]) * tanhf(cv);
            u16 hh = f2bf(hv);
            hn_hi[gidx] = hh;
            hn_lo[gidx] = f2bf(hv - bf2f(hh));
        }
    }
}

// ---------------- latent 1: mean/logvar/z (fp32 scalar, once) ----------------
__global__ __launch_bounds__(256) void latent1(
    const u16* he,
    const float* __restrict__ W_mu, const float* __restrict__ b_mu,
    const float* __restrict__ W_lv, const float* __restrict__ b_lv,
    const float* __restrict__ eps, float* z, float* out)
{
    __shared__ float hs[16 * 512];
    const int row0 = blockIdx.x * 16;
    const int tid = threadIdx.x;
    const u16* hf_hi = he + ((1 * 2 + 0) * 2 + 0) * HE_BLK;
    const u16* hf_lo = he + ((1 * 2 + 0) * 2 + 1) * HE_BLK;
    const u16* hb_hi = he + ((1 * 2 + 1) * 2 + 0) * HE_BLK;
    const u16* hb_lo = he + ((1 * 2 + 1) * 2 + 1) * HE_BLK;
    for (int i = tid; i < 8192; i += 256) {
        int r = i >> 9, col = i & 511;
        int gi = (row0 + r) * 256;
        float v;
        if (col < 256) v = bf2f(hf_hi[gi + col]) + bf2f(hf_lo[gi + col]);
        else { int cc = col - 256; v = bf2f(hb_hi[gi + cc]) + bf2f(hb_lo[gi + cc]); }
        hs[i] = v;
    }
    __syncthreads();
    for (int p = tid; p < 2048; p += 256) {
        int r = p >> 7, cc = p & 127;
        const float* hr = hs + r * 512;
        float m = 0, lv = 0;
#pragma unroll 8
        for (int k = 0; k < 512; ++k) {
            float hv = hr[k];
            m  += hv * W_mu[k * 128 + cc];
            lv += hv * W_lv[k * 128 + cc];
        }
        m += b_mu[cc]; lv += b_lv[cc];
        int b = row0 + r;
        out[512002 + b * 128 + cc] = m;
        out[577538 + b * 128 + cc] = lv;
        z[b * 128 + cc] = m + __expf(0.5f * lv) * eps[b * 128 + cc];
    }
}

// ---------------- latent 2: h0/c0 = tanh(z@W_fc_in+b) split; zpre = z@dec_Wih[5:] + dec_b ----------------
__global__ __launch_bounds__(256) void latent2(
    const float* __restrict__ z, const float* __restrict__ W_fc, const float* __restrict__ b_fc,
    const float* __restrict__ dWih, const float* __restrict__ dec_b,
    u16* hd, float* c_d, float* zpre)
{
    __shared__ float zs[16 * 128];
    const int row0 = blockIdx.y * 16;
    const int tid = threadIdx.x;
    u16* h0_hi = hd + 0;
    u16* h0_lo = hd + HD_BLK;
    {
        float4* dst = (float4*)zs;
        const float4* src = (const float4*)(z + row0 * 128);
        for (int i = tid; i < 512; i += 256) dst[i] = src[i];
    }
    __syncthreads();
    const int colbase = blockIdx.x * 128;
    for (int p = tid; p < 16 * 128; p += 256) {
        int r = p >> 7, cl = p & 127;
        int col = colbase + cl;
        const float* zr = zs + r * 128;
        int b = row0 + r;
        if (col < 1024) {
            float acc = 0;
#pragma unroll 8
            for (int k = 0; k < 128; ++k) acc += zr[k] * W_fc[k * 1024 + col];
            float v = tanhf(acc + b_fc[col]);
            if (col < 512) {
                u16 hh = f2bf(v);
                h0_hi[b * 512 + col] = hh;
                h0_lo[b * 512 + col] = f2bf(v - bf2f(hh));
            } else c_d[b * 512 + (col - 512)] = v;
        } else {
            int n = col - 1024;
            float acc = 0;
#pragma unroll 8
            for (int k = 0; k < 128; ++k) acc += zr[k] * dWih[(5 + k) * 2048 + n];
            zpre[b * 2048 + n] = acc + dec_b[n];
        }
    }
}

// ---------------- fused decoder step ----------------
// MODE 0: first step (no out phase). MODE 1: out(s-1) + cell(s). MODE 2: out(198) only.
template<int MODE>
__global__ __launch_bounds__(256) void dec_step_m(
    const float* __restrict__ x, const int* __restrict__ N_s,
    const float* __restrict__ dec_Wih, const float* __restrict__ b_out,
    const u16* whhT,   // [part][2048*512]
    const u16* woutT,  // [part][128*512]
    const float* zpre,
    u16* hd,           // [buf][part][512*512]
    float* c_d, float* out, int s)
{
    const int j0 = blockIdx.x * 32;
    const int row0 = blockIdx.y * 32;
    const int pb = s & 1, nb = pb ^ 1;
    const u16* hp_hi = hd + (pb * 2 + 0) * HD_BLK;
    const u16* hp_lo = hd + (pb * 2 + 1) * HD_BLK;
    u16* hn_hi = hd + (nb * 2 + 0) * HD_BLK;
    u16* hn_lo = hd + (nb * 2 + 1) * HD_BLK;

    __shared__ __align__(16) char smem[40960];
    u16* As_hi = (u16*)smem;
    u16* As_lo = As_hi + 2048;
    u16* Bs_hi = As_lo + 2048;
    u16* Bs_lo = Bs_hi + 8192;
    float (*ysL)[128] = (float(*)[128])(smem + 8192);       // aliases Bs_hi (16KB)
    float (*gL)[32][32] = (float(*)[32][32])(smem + 8192);  // same region, phase-2 epilogue
    __shared__ float sxs[32][5];
    __shared__ float xtL[32][5];
    __shared__ float dwL[5][128];
    __shared__ float redL[64];

    const int tid = threadIdx.x;
    const int wv = tid >> 6, lane = tid & 63;

    if (MODE != 2 && tid < 128) {
#pragma unroll
        for (int i = 0; i < 5; ++i) dwL[i][tid] = dec_Wih[i * 2048 + (tid >> 5) * 512 + j0 + (tid & 31)];
    }
    if constexpr (MODE == 0) {
        if (tid < 160) { int r = tid / 5, i = tid % 5; sxs[r][i] = (i == 2) ? 1.0f : 0.0f; }
    } else {
        const int sy = s - 1;
        if (tid < 160) { int r = tid / 5, i = tid % 5; xtL[r][i] = x[(sy + 1) * 2560 + (row0 + r) * 5 + i]; }
        // ---- phase 1: y = h_prev @ W_out ----
        fx4 acc[2][2] = {};
        for (int ch = 0; ch < 8; ++ch) {
            if (ch) __syncthreads();
            const int kb = ch * 64;
            stageA(As_hi, hp_hi + row0 * 512 + kb, 512);
            stageA(As_lo, hp_lo + row0 * 512 + kb, 512);
            stageB(Bs_hi, woutT, 512, 32, 0, kb);
            stageB(Bs_lo, woutT + 65536, 512, 32, 0, kb);
            __syncthreads();
            gemm_chunk(As_hi, As_lo, Bs_hi, Bs_lo, wv, lane, acc);
        }
        __syncthreads();
#pragma unroll
        for (int mt = 0; mt < 2; ++mt)
#pragma unroll
            for (int nt = 0; nt < 2; ++nt)
#pragma unroll
                for (int r2 = 0; r2 < 4; ++r2) {
                    int bl = mt * 16 + (lane >> 4) * 4 + r2;
                    int col = wv * 32 + nt * 16 + (lane & 15);
                    ysL[bl][col] = acc[mt][nt][r2] + ((col < 123) ? b_out[col] : 0.0f);
                }
        __syncthreads();
        // ---- mixture / losses / stroke ----
        {
            const int row = tid >> 3, g = tid & 7;
            const float* yr = ysL[row];
            const float dx = xtL[row][0], dy = xtL[row][1];
            float pm = -1e30f;
            for (int cg = g; cg < NMIX; cg += 8) pm = fmaxf(pm, yr[cg * 6]);
            pm = fmaxf(pm, __shfl_xor(pm, 1));
            pm = fmaxf(pm, __shfl_xor(pm, 2));
            pm = fmaxf(pm, __shfl_xor(pm, 4));
            float S = 0, gp = 0, gx = 0, gy = 0;
            for (int cg = g; cg < NMIX; cg += 8) {
                float ph = yr[cg * 6], mux = yr[cg * 6 + 1], muy = yr[cg * 6 + 2];
                float ssx = __expf(yr[cg * 6 + 3]), ssy = __expf(yr[cg * 6 + 4]);
                float rho = tanhf(yr[cg * 6 + 5]);
                float e = __expf(ph - pm);
                float zx = (dx - mux) / ssx, zy = (dy - muy) / ssy;
                float om = 1.0f - rho * rho;
                float pdf = __expf(-(zx * zx + zy * zy - 2.0f * rho * zx * zy) / (2.0f * om))
                            * (0.15915494309189535f / (ssx * ssy * sqrtf(om)));
                S += e; gp += e * pdf; gx += e * mux; gy += e * muy;
            }
#pragma unroll
            for (int off = 1; off < 8; off <<= 1) {
                S += __shfl_xor(S, off); gp += __shfl_xor(gp, off);
                gx += __shfl_xor(gx, off); gy += __shfl_xor(gy, off);
            }
            if (g == 0) {
                const int b = row0 + row;
                float q0 = yr[120], q1 = yr[121], q2 = yr[122];
                float qm = fmaxf(q0, fmaxf(q1, q2));
                float lse = qm + logf(__expf(q0 - qm) + __expf(q1 - qm) + __expf(q2 - qm));
                float pl = -(xtL[row][2] * (q0 - lse) + xtL[row][3] * (q1 - lse) + xtL[row][4] * (q2 - lse));
                int len = N_s[b];
                float ol = ((sy + 1) < len) ? -logf(gp / S + 1e-6f) : 0.0f;
                int am = 0; float bv = q0;
                if (q1 > bv) { bv = q1; am = 1; }
                if (q2 > bv) { bv = q2; am = 2; }
                float s0, s1, s2, s3, s4;
                if ((sy + 1) > len) { s0 = s1 = s2 = s3 = 0.0f; s4 = 1.0f; }
                else { s0 = gx / S; s1 = gy / S; s2 = (am == 0); s3 = (am == 1); s4 = (am == 2); }
                sxs[row][0] = s0; sxs[row][1] = s1; sxs[row][2] = s2; sxs[row][3] = s3; sxs[row][4] = s4;
                if (blockIdx.x == 0) {
                    float* so = out + sy * 2560 + b * 5;
                    so[0] = s0; so[1] = s1; so[2] = s2; so[3] = s3; so[4] = s4;
                    redL[row] = pl; redL[32 + row] = ol;
                }
            }
        }
        __syncthreads();
        if (blockIdx.x == 0 && tid == 0) {
            float spl = 0, sol = 0;
            for (int r = 0; r < 32; ++r) { spl += redL[r]; sol += redL[32 + r]; }
            atomicAdd(out + 512001, spl * (1.0f / 102400.0f));
            atomicAdd(out + 512000, sol * (1.0f / 102400.0f));
        }
    }
    if constexpr (MODE == 2) return;

    __syncthreads();  // protect Bs region (ysL reads done) before phase-2 staging
    // ---- phase 2: gates = h_prev @ Whh ----
    fx4 acc2[2][2] = {};
    for (int ch = 0; ch < 8; ++ch) {
        if (ch) __syncthreads();
        const int kb = ch * 64;
        stageA(As_hi, hp_hi + row0 * 512 + kb, 512);
        stageA(As_lo, hp_lo + row0 * 512 + kb, 512);
        stageB(Bs_hi, whhT, 512, 512, j0, kb);
        stageB(Bs_lo, whhT + 1048576, 512, 512, j0, kb);
        __syncthreads();
        gemm_chunk(As_hi, As_lo, Bs_hi, Bs_lo, wv, lane, acc2);
    }
    __syncthreads();
#pragma unroll
    for (int mt = 0; mt < 2; ++mt)
#pragma unroll
        for (int nt = 0; nt < 2; ++nt)
#pragma unroll
            for (int r2 = 0; r2 < 4; ++r2)
                gL[wv][mt * 16 + (lane >> 4) * 4 + r2][nt * 16 + (lane & 15)] = acc2[mt][nt][r2];
    __syncthreads();
    {
        const int j = tid & 31, rq = tid >> 5;
#pragma unroll
        for (int ii = 0; ii < 4; ++ii) {
            const int b = rq + ii * 8;
            const int gb = row0 + b;
            float gv[4];
#pragma unroll
            for (int g = 0; g < 4; ++g) {
                float sum = gL[g][b][j] + zpre[gb * 2048 + g * 512 + j0 + j];
#pragma unroll
                for (int i = 0; i < 5; ++i) sum += sxs[b][i] * dwL[i][g * 32 + j];
                gv[g] = sum;
            }
            const int gidx = gb * 512 + j0 + j;
            float cv = c_d[gidx];
            cv = sigm(gv[1]) * cv + sigm(gv[0]) * tanhf(gv[2]);
            c_d[gidx] = cv;
            float hv = sigm(gv[3]) * tanhf(cv);
            u16 hh = f2bf(hv);
            hn_hi[gidx] = hh;
            hn_lo[gidx] = f2bf(hv - bf2f(hh));
        }
    }
}

extern "C" void kernel_launch(void* const* d_in, const int* in_sizes, int n_in,
                              void* d_out_, int out_size, void* d_ws, size_t ws_size,
                              hipStream_t stream) {
    const float* x         = (const float*)d_in[0];
    const int*   N_s       = (const int*)  d_in[1];
    const float* eps       = (const float*)d_in[2];
    const float* enc_Wih_f = (const float*)d_in[3];
    const float* enc_Whh_f = (const float*)d_in[4];
    const float* enc_b_f   = (const float*)d_in[5];
    const float* enc_Wih_b = (const float*)d_in[6];
    const float* enc_Whh_b = (const float*)d_in[7];
    const float* enc_b_b   = (const float*)d_in[8];
    const float* W_mu      = (const float*)d_in[9];
    const float* b_mu      = (const float*)d_in[10];
    const float* W_logvar  = (const float*)d_in[11];
    const float* b_logvar  = (const float*)d_in[12];
    const float* W_fc_in   = (const float*)d_in[13];
    const float* b_fc_in   = (const float*)d_in[14];
    const float* dec_Wih   = (const float*)d_in[15];
    const float* dec_Whh   = (const float*)d_in[16];
    const float* dec_b     = (const float*)d_in[17];
    const float* W_out     = (const float*)d_in[18];
    const float* b_out     = (const float*)d_in[19];
    float* out = (float*)d_out_;
    float* ws  = (float*)d_ws;

    float* c_f  = ws;                 // 131072
    float* c_d  = ws + 262144;        // 262144
    float* zpre = ws + 524288;        // 1048576
    float* z    = ws + 1572864;       // 65536
    u16* U     = (u16*)(ws + 1638400);
    u16* he    = U;                   // 8 * 131072
    u16* hd    = U + 1048576;         // 4 * 262144
    u16* encT  = U + 2097152;         // 4 * 262144
    u16* decT  = U + 3145728;         // 2 * 1048576
    u16* woutT = U + 5242880;         // 2 * 65536

    // zero: enc c (both dirs), enc h buf0 (hi+lo both dirs), d_out tail (stroke row 199 + losses)
    hipMemsetAsync(c_f, 0, 262144 * sizeof(float), stream);
    hipMemsetAsync(he, 0, 4 * HE_BLK * sizeof(u16), stream);
    hipMemsetAsync(out + 509440, 0, 2562 * sizeof(float), stream);

    // weight prep: split + transpose
    prep_split_T<<<1024, 256, 0, stream>>>(enc_Whh_f, encT,           encT + 262144,  256, 1024, 1024);
    prep_split_T<<<1024, 256, 0, stream>>>(enc_Whh_b, encT + 524288,  encT + 786432,  256, 1024, 1024);
    prep_split_T<<<4096, 256, 0, stream>>>(dec_Whh,   decT,           decT + 1048576, 512, 2048, 2048);
    prep_split_T<<<256,  256, 0, stream>>>(W_out,     woutT,          woutT + 65536,  512, 123, 128);

    for (int t = 0; t <= NMAX; ++t)
        enc_step_m<<<dim3(8, 16, 2), 256, 0, stream>>>(
            x, enc_Wih_f, enc_b_f, enc_Wih_b, enc_b_b, encT, he, c_f, t);

    latent1<<<32, 256, 0, stream>>>(he, W_mu, b_mu, W_logvar, b_logvar, eps, z, out);
    latent2<<<dim3(24, 32), 256, 0, stream>>>(z, W_fc_in, b_fc_in, dec_Wih, dec_b, hd, c_d, zpre);

    dec_step_m<0><<<dim3(16, 16), 256, 0, stream>>>(x, N_s, dec_Wih, b_out, decT, woutT, zpre, hd, c_d, out, 0);
    for (int s = 1; s <= NMAX - 2; ++s)
        dec_step_m<1><<<dim3(16, 16), 256, 0, stream>>>(x, N_s, dec_Wih, b_out, decT, woutT, zpre, hd, c_d, out, s);
    dec_step_m<2><<<dim3(1, 16), 256, 0, stream>>>(x, N_s, dec_Wih, b_out, decT, woutT, zpre, hd, c_d, out, NMAX - 1);
}